// Round 9
// baseline (809.147 us; speedup 1.0000x reference)
//
#include <hip/hip_runtime.h>

#define NEG_SLOPE 0.2f
#define PSHIFT 15          // partition = row >> 15 (32768 rows/partition)
#define MAXP 16            // max partitions (NT<=512K; actual used = 10)
#define EPB 2048           // edges per block in bin_scatter

// ===========================================================================
// Combined destination space:
// rows [0,n0)=S0a(x0), [n0,2n0)=S0b(x1), [2n0,2n0+n3)=S3a(x3), [2n0+n3,NT)=S3b(x2)
// CSR pipeline: bin_sizes -> scan16 -> bin_scatter -> hist_part ->
//               chunk_sum/scan_bsum/chunk_scan -> part_fill
// ===========================================================================

__device__ __forceinline__ int decode_dst(int j, const int* ad0, const int* d1,
                                          const int* ad3, const int* d2,
                                          int E0, int E01, int E3,
                                          int n0, int n3) {
    if (j < E0) return ad0[j];
    if ((j -= E0) < E01) return n0 + d1[j];
    if ((j -= E01) < E3) return 2 * n0 + ad3[j];
    return 2 * n0 + n3 + d2[j - E3];
}

__device__ __forceinline__ int decode_src(int j, const int* as0, const int* s1,
                                          const int* as3, const int* s2,
                                          int E0, int E01, int E3) {
    if (j < E0) return as0[j];
    if ((j -= E0) < E01) return s1[j];
    if ((j -= E01) < E3) return as3[j];
    return s2[j - E3];
}

// per-partition edge counts (LDS 16-counter hist, one streaming read of dests)
__global__ __launch_bounds__(256) void bin_sizes(const int* __restrict__ ad0,
                                                 const int* __restrict__ d1,
                                                 const int* __restrict__ ad3,
                                                 const int* __restrict__ d2,
                                                 int E0, int E01, int E3, int E23,
                                                 int n0, int n3,
                                                 int* __restrict__ gsizes) {
    __shared__ int h[MAXP];
    if (threadIdx.x < MAXP) h[threadIdx.x] = 0;
    __syncthreads();
    int T = E0 + E01 + E3 + E23;
    int stride = gridDim.x * 256;
    for (int i = blockIdx.x * 256 + threadIdx.x; i < T; i += stride) {
        int cd = decode_dst(i, ad0, d1, ad3, d2, E0, E01, E3, n0, n3);
        atomicAdd(&h[cd >> PSHIFT], 1);
    }
    __syncthreads();
    if (threadIdx.x < MAXP) atomicAdd(&gsizes[threadIdx.x], h[threadIdx.x]);
}

// serial 16-element exclusive scan -> pstart, init bucket cursors
__global__ void scan16(const int* __restrict__ gsizes,
                       int* __restrict__ pstart, int* __restrict__ bcursor) {
    if (threadIdx.x == 0 && blockIdx.x == 0) {
        int run = 0;
        for (int p = 0; p < MAXP; ++p) {
            pstart[p] = run;
            bcursor[p] = run;
            run += gsizes[p];
        }
        pstart[MAXP] = run;
    }
}

// bin edges into per-partition buckets of (cd,src) pairs. Per block: LDS hist
// of its 2048-edge chunk, one global atomic per (block,partition) to reserve
// contiguous space, then dense int2 writes (full lines, no RMW).
__global__ __launch_bounds__(256) void bin_scatter(const int* __restrict__ ad0,
                                                   const int* __restrict__ as0,
                                                   const int* __restrict__ d1,
                                                   const int* __restrict__ s1,
                                                   const int* __restrict__ ad3,
                                                   const int* __restrict__ as3,
                                                   const int* __restrict__ d2,
                                                   const int* __restrict__ s2,
                                                   int E0, int E01, int E3, int E23,
                                                   int n0, int n3,
                                                   int* __restrict__ bcursor,
                                                   int2* __restrict__ bucket) {
    __shared__ int h[MAXP], base[MAXP], loc[MAXP];
    int t = threadIdx.x;
    if (t < MAXP) { h[t] = 0; loc[t] = 0; }
    __syncthreads();

    int T = E0 + E01 + E3 + E23;
    int b0 = blockIdx.x * EPB;
    int cd[EPB / 256], sv[EPB / 256];
    bool ok[EPB / 256];
#pragma unroll
    for (int j = 0; j < EPB / 256; ++j) {
        int idx = b0 + j * 256 + t;
        ok[j] = idx < T;
        if (ok[j]) {
            cd[j] = decode_dst(idx, ad0, d1, ad3, d2, E0, E01, E3, n0, n3);
            sv[j] = decode_src(idx, as0, s1, as3, s2, E0, E01, E3);
            atomicAdd(&h[cd[j] >> PSHIFT], 1);
        }
    }
    __syncthreads();
    if (t < MAXP && h[t] > 0) base[t] = atomicAdd(&bcursor[t], h[t]);
    __syncthreads();
#pragma unroll
    for (int j = 0; j < EPB / 256; ++j) {
        if (ok[j]) {
            int p = cd[j] >> PSHIFT;
            int o = atomicAdd(&loc[p], 1);
            bucket[base[p] + o] = make_int2(cd[j], sv[j]);
        }
    }
}

// per-row counts, partition-local: cohort p (blockIdx%16, pins XCD) reads only
// its bucket; atomics land in a <=128KB L2-local counts window.
__global__ __launch_bounds__(256) void hist_part(const int2* __restrict__ bucket,
                                                 const int* __restrict__ pstart,
                                                 int* __restrict__ counts, int BPC) {
    int p = blockIdx.x & (MAXP - 1);
    int r = blockIdx.x >> 4;
    int beg = pstart[p], end = pstart[p + 1];
    int stride = BPC * 256;
    for (int i = beg + r * 256 + (int)threadIdx.x; i < end; i += stride)
        atomicAdd(&counts[bucket[i].x], 1);
}

// per-2048-row chunk sums
__global__ __launch_bounds__(256) void chunk_sum(const int* __restrict__ counts,
                                                 int* __restrict__ bsum, int NT) {
    __shared__ int red[256];
    int base = blockIdx.x * 2048;
    int t = threadIdx.x;
    int s = 0;
#pragma unroll
    for (int j = 0; j < 8; ++j) {
        int idx = base + j * 256 + t;
        if (idx < NT) s += counts[idx];
    }
    red[t] = s;
    __syncthreads();
    for (int off = 128; off > 0; off >>= 1) {
        if (t < off) red[t] += red[t + off];
        __syncthreads();
    }
    if (t == 0) bsum[blockIdx.x] = red[0];
}

// exclusive scan of chunk sums (nb <= 256)
__global__ __launch_bounds__(256) void scan_bsum(const int* __restrict__ bsum,
                                                 int* __restrict__ bbase, int nb) {
    __shared__ int sh[256];
    int t = threadIdx.x;
    int v = (t < nb) ? bsum[t] : 0;
    sh[t] = v;
    __syncthreads();
    for (int off = 1; off < 256; off <<= 1) {
        int add = (t >= off) ? sh[t - off] : 0;
        __syncthreads();
        sh[t] += add;
        __syncthreads();
    }
    if (t < nb) bbase[t] = sh[t] - v;  // exclusive
}

// per-chunk exclusive scan + chunk base; writes offsets AND cursors
__global__ __launch_bounds__(256) void chunk_scan(const int* __restrict__ counts,
                                                  const int* __restrict__ bbase,
                                                  int* __restrict__ offsets,
                                                  int* __restrict__ cursors,
                                                  int NT, int E_total) {
    __shared__ int tsum[256];
    int t = threadIdx.x;
    int base = blockIdx.x * 2048 + t * 8;
    int v[8];
    int s = 0;
#pragma unroll
    for (int j = 0; j < 8; ++j) {
        int idx = base + j;
        v[j] = (idx < NT) ? counts[idx] : 0;
        s += v[j];
    }
    tsum[t] = s;
    __syncthreads();
    for (int off = 1; off < 256; off <<= 1) {
        int add = (t >= off) ? tsum[t - off] : 0;
        __syncthreads();
        tsum[t] += add;
        __syncthreads();
    }
    int run = bbase[blockIdx.x] + tsum[t] - s;
#pragma unroll
    for (int j = 0; j < 8; ++j) {
        int idx = base + j;
        if (idx < NT) { offsets[idx] = run; cursors[idx] = run; }
        run += v[j];
    }
    if (blockIdx.x == 0 && t == 0) offsets[NT] = E_total;
}

// CSR fill, partition-local: cohort p reads its bucket, writes src into its
// ~1-2MB edge_src window; cursor + write lines stay L2-resident (one XCD),
// no streaming traffic to evict them -> full-line merges.
__global__ __launch_bounds__(256) void part_fill(const int2* __restrict__ bucket,
                                                 const int* __restrict__ pstart,
                                                 int* __restrict__ cursors,
                                                 int* __restrict__ edge_src, int BPC) {
    int p = blockIdx.x & (MAXP - 1);
    int r = blockIdx.x >> 4;
    int beg = pstart[p], end = pstart[p + 1];
    int stride = BPC * 256;
    for (int i = beg + r * 256 + (int)threadIdx.x; i < end; i += stride) {
        int2 e = bucket[i];
        int pos = atomicAdd(&cursors[e.x], 1);
        edge_src[pos] = e.y;
    }
}

// ===========================================================================
// gather4: 16 rows per block (16 lanes x float4 per row), 2 edges in flight
// per row. Fully writes both halves of agg0/agg3 (no memset needed).
// ===========================================================================
__global__ __launch_bounds__(256) void gather4(const int* __restrict__ offsets,
                                               const int* __restrict__ edge_src,
                                               const float* __restrict__ x0,
                                               const float* __restrict__ x1,
                                               const float* __restrict__ x2,
                                               const float* __restrict__ x3,
                                               float* __restrict__ agg0,
                                               float* __restrict__ agg3,
                                               int n0, int n3) {
    const int NT = 2 * n0 + 2 * n3;
    int row = blockIdx.x * 16 + (threadIdx.x >> 4);
    int c4 = (threadIdx.x & 15) * 4;
    if (row >= NT) return;
    const float* xs;
    float* outp;
    if (row < n0)               { xs = x0; outp = &agg0[(size_t)row * 128]; }
    else if (row < 2 * n0)      { xs = x1; outp = &agg0[(size_t)(row - n0) * 128 + 64]; }
    else if (row < 2 * n0 + n3) { xs = x3; outp = &agg3[(size_t)(row - 2 * n0) * 128]; }
    else                        { xs = x2; outp = &agg3[(size_t)(row - 2 * n0 - n3) * 128 + 64]; }

    int k = offsets[row], end = offsets[row + 1];
    float4 acc = make_float4(0.f, 0.f, 0.f, 0.f);
    for (; k + 2 <= end; k += 2) {
        int i0 = edge_src[k];
        int i1 = edge_src[k + 1];
        float4 a = *(const float4*)&xs[(size_t)i0 * 64 + c4];
        float4 b = *(const float4*)&xs[(size_t)i1 * 64 + c4];
        acc.x += a.x + b.x;
        acc.y += a.y + b.y;
        acc.z += a.z + b.z;
        acc.w += a.w + b.w;
    }
    if (k < end) {
        int i0 = edge_src[k];
        float4 a = *(const float4*)&xs[(size_t)i0 * 64 + c4];
        acc.x += a.x; acc.y += a.y; acc.z += a.z; acc.w += a.w;
    }
    *(float4*)&outp[c4] = acc;
}

// ===========================================================================
// combine_w2: WC0 = [W_hbs0 @ F0^T ; W_s01 @ F0^T], WC3 likewise; one launch.
// ===========================================================================
__global__ __launch_bounds__(256) void combine_w2(const float* __restrict__ Wtop0,
                                                  const float* __restrict__ Wbot0,
                                                  const float* __restrict__ F0,
                                                  float* __restrict__ WC0,
                                                  const float* __restrict__ Wtop3,
                                                  const float* __restrict__ Wbot3,
                                                  const float* __restrict__ F3,
                                                  float* __restrict__ WC3) {
    int gi = blockIdx.x * 256 + threadIdx.x;   // 0..32767
    int which = gi >> 14;
    int i = gi & 16383;
    const float* Wtop = which ? Wtop3 : Wtop0;
    const float* Wbot = which ? Wbot3 : Wbot0;
    const float* F = which ? F3 : F0;
    float* WC = which ? WC3 : WC0;
    int k = i >> 7;
    int c = i & 127;
    const float* wrow = (k < 64) ? &Wtop[(size_t)k * 128] : &Wbot[(size_t)(k - 64) * 128];
    const float* frow = &F[(size_t)c * 128];
    float s = 0.f;
#pragma unroll 8
    for (int j = 0; j < 128; j += 4) {
        float4 w = *(const float4*)&wrow[j];
        float4 f = *(const float4*)&frow[j];
        s = fmaf(w.x, f.x, s);
        s = fmaf(w.y, f.y, s);
        s = fmaf(w.z, f.z, s);
        s = fmaf(w.w, f.w, s);
    }
    WC[(size_t)k * 128 + c] = s;
}

// ===========================================================================
// fc_lrelu: Y[n x 128] = lrelu(A[n x 128] @ WC + b); WC k-major.
// ===========================================================================
__global__ __launch_bounds__(256) void fc_lrelu(const float* __restrict__ A,
                                                const float* __restrict__ WC,
                                                const float* __restrict__ bias,
                                                float* __restrict__ Y, int n) {
    __shared__ float WS[64][128];
    __shared__ float XS[64][68];
    const int t = threadIdx.x;
    const int row0 = blockIdx.x * 64;
    const int c = (t & 31) * 4;
    const int rbase = (t >> 5) * 8;
    float acc[8][4];
#pragma unroll
    for (int i = 0; i < 8; ++i)
#pragma unroll
        for (int j = 0; j < 4; ++j) acc[i][j] = 0.f;

    for (int p = 0; p < 2; ++p) {
        __syncthreads();
        const float4* Wp4 = (const float4*)(WC + (size_t)p * 64 * 128);
        float4* WS4 = (float4*)&WS[0][0];
        for (int i = t; i < 2048; i += 256) WS4[i] = Wp4[i];
        for (int i = t; i < 64 * 16; i += 256) {
            int r = i >> 4, c4 = i & 15;
            float4 v = make_float4(0.f, 0.f, 0.f, 0.f);
            if (row0 + r < n)
                v = *(const float4*)&A[(size_t)(row0 + r) * 128 + p * 64 + c4 * 4];
            *(float4*)&XS[r][c4 * 4] = v;
        }
        __syncthreads();

#pragma unroll 4
        for (int k = 0; k < 64; k += 4) {
            float4 w[4];
            w[0] = *(const float4*)&WS[k + 0][c];
            w[1] = *(const float4*)&WS[k + 1][c];
            w[2] = *(const float4*)&WS[k + 2][c];
            w[3] = *(const float4*)&WS[k + 3][c];
#pragma unroll
            for (int i = 0; i < 8; ++i) {
                float4 x = *(const float4*)&XS[rbase + i][k];
                float xs[4] = {x.x, x.y, x.z, x.w};
#pragma unroll
                for (int kk = 0; kk < 4; ++kk) {
                    acc[i][0] = fmaf(xs[kk], w[kk].x, acc[i][0]);
                    acc[i][1] = fmaf(xs[kk], w[kk].y, acc[i][1]);
                    acc[i][2] = fmaf(xs[kk], w[kk].z, acc[i][2]);
                    acc[i][3] = fmaf(xs[kk], w[kk].w, acc[i][3]);
                }
            }
        }
    }

    float4 b = *(const float4*)&bias[c];
    float bs[4] = {b.x, b.y, b.z, b.w};
#pragma unroll
    for (int i = 0; i < 8; ++i) {
        int r = row0 + rbase + i;
        if (r < n) {
            float o[4];
#pragma unroll
            for (int j = 0; j < 4; ++j) {
                float v = acc[i][j] + bs[j];
                o[j] = v > 0.f ? v : NEG_SLOPE * v;
            }
            *(float4*)&Y[(size_t)r * 128 + c] = make_float4(o[0], o[1], o[2], o[3]);
        }
    }
}

// one kernel for all three passthrough copies (float4 granularity)
__global__ __launch_bounds__(256) void copy_all(const float4* __restrict__ s1, float4* __restrict__ o1, int m1,
                                                const float4* __restrict__ s2, float4* __restrict__ o2, int m2,
                                                const float4* __restrict__ s4, float4* __restrict__ o4, int m4) {
    int total = m1 + m2 + m4;
    int i = blockIdx.x * 256 + threadIdx.x;
    int stride = gridDim.x * 256;
    for (; i < total; i += stride) {
        int j = i;
        if (j < m1) { o1[j] = s1[j]; }
        else if ((j -= m1) < m2) { o2[j] = s2[j]; }
        else { j -= m2; o4[j] = s4[j]; }
    }
}

extern "C" void kernel_launch(void* const* d_in, const int* in_sizes, int n_in,
                              void* d_out, int out_size, void* d_ws, size_t ws_size,
                              hipStream_t stream) {
    const float* x0 = (const float*)d_in[0];
    const float* x1 = (const float*)d_in[1];
    const float* x2 = (const float*)d_in[2];
    const float* x3 = (const float*)d_in[3];
    const float* x4 = (const float*)d_in[4];
    const int* adj0 = (const int*)d_in[5];
    const int* adj3 = (const int*)d_in[6];
    const int* inc01_t = (const int*)d_in[7];
    const int* inc01_s = (const int*)d_in[8];
    const int* inc23_t = (const int*)d_in[9];
    const int* inc23_s = (const int*)d_in[10];
    const float* W_hbs0 = (const float*)d_in[11];
    const float* W_hbs3 = (const float*)d_in[12];
    const float* W_s01 = (const float*)d_in[13];
    const float* W_t23 = (const float*)d_in[14];
    const float* fc0_W = (const float*)d_in[15];
    const float* fc0_b = (const float*)d_in[16];
    const float* fc3_W = (const float*)d_in[17];
    const float* fc3_b = (const float*)d_in[18];

    const int n0 = in_sizes[0] / 64, n1 = in_sizes[1] / 64;
    const int n2 = in_sizes[2] / 64, n3 = in_sizes[3] / 64, n4 = in_sizes[4] / 64;
    const int E0 = in_sizes[5] / 2, E3 = in_sizes[6] / 2;
    const int E01 = in_sizes[7], E23 = in_sizes[9];
    const int NT = 2 * n0 + 2 * n3;
    const int E_total = E0 + E01 + E3 + E23;
    const int nb = (NT + 2047) / 2048;
    const int BPC = 64;   // blocks per partition cohort

    // workspace layout
    float* ws = (float*)d_ws;
    size_t off = 0;
    float* agg0 = ws + off; off += (size_t)n0 * 128;
    float* agg3 = ws + off; off += (size_t)n3 * 128;
    float* wc0 = ws + off;  off += 16384;
    float* wc3 = ws + off;  off += 16384;
    int* counts = (int*)(ws + off);   off += NT;
    int* gsizes = (int*)(ws + off);   off += MAXP;       // memset covers counts+gsizes
    int* offsets = (int*)(ws + off);  off += NT + 1;
    int* cursors = (int*)(ws + off);  off += NT;
    int* bsum = (int*)(ws + off);     off += 256;
    int* bbase = (int*)(ws + off);    off += 256;
    int* pstart = (int*)(ws + off);   off += MAXP + 1;
    int* bcursor = (int*)(ws + off);  off += MAXP;
    off = (off + 1) & ~(size_t)1;                         // 8B align for int2
    int2* bucket = (int2*)(ws + off); off += (size_t)E_total * 2;
    int* edge_src = (int*)(ws + off); off += E_total;

    float* out = (float*)d_out;
    float* o_x0 = out;
    float* o_x1 = o_x0 + (size_t)n0 * 128;
    float* o_x2 = o_x1 + (size_t)n1 * 64;
    float* o_x3 = o_x2 + (size_t)n2 * 64;
    float* o_x4 = o_x3 + (size_t)n3 * 128;

    // ---- CSR build via partition binning ----
    hipMemsetAsync(counts, 0, (size_t)(NT + MAXP) * sizeof(int), stream);
    bin_sizes<<<2048, 256, 0, stream>>>(adj0, inc01_t, adj3, inc23_s,
                                        E0, E01, E3, E23, n0, n3, gsizes);
    scan16<<<1, 64, 0, stream>>>(gsizes, pstart, bcursor);
    bin_scatter<<<(E_total + EPB - 1) / EPB, 256, 0, stream>>>(
        adj0, adj0 + E0, inc01_t, inc01_s, adj3, adj3 + E3, inc23_s, inc23_t,
        E0, E01, E3, E23, n0, n3, bcursor, bucket);
    hist_part<<<MAXP * BPC, 256, 0, stream>>>(bucket, pstart, counts, BPC);
    chunk_sum<<<nb, 256, 0, stream>>>(counts, bsum, NT);
    scan_bsum<<<1, 256, 0, stream>>>(bsum, bbase, nb);
    chunk_scan<<<nb, 256, 0, stream>>>(counts, bbase, offsets, cursors, NT, E_total);
    part_fill<<<MAXP * BPC, 256, 0, stream>>>(bucket, pstart, cursors, edge_src, BPC);

    // ---- gather-reduce (writes agg0/agg3 fully) ----
    gather4<<<(NT + 15) / 16, 256, 0, stream>>>(offsets, edge_src, x0, x1, x2, x3,
                                                agg0, agg3, n0, n3);

    // ---- combined weights + fused FC ----
    combine_w2<<<128, 256, 0, stream>>>(W_hbs0, W_s01, fc0_W, wc0,
                                        W_hbs3, W_t23, fc3_W, wc3);
    fc_lrelu<<<(n0 + 63) / 64, 256, 0, stream>>>(agg0, wc0, fc0_b, o_x0, n0);
    fc_lrelu<<<(n3 + 63) / 64, 256, 0, stream>>>(agg3, wc3, fc3_b, o_x3, n3);

    // ---- passthrough outputs (one kernel) ----
    copy_all<<<8192, 256, 0, stream>>>((const float4*)x1, (float4*)o_x1, n1 * 16,
                                       (const float4*)x2, (float4*)o_x2, n2 * 16,
                                       (const float4*)x4, (float4*)o_x4, n4 * 16);
}